// Round 5
// baseline (131.220 us; speedup 1.0000x reference)
//
#include <hip/hip_runtime.h>
#include <math.h>

#define NG 1024
#define NSEG 8
#define SEG_LEN 128            // gaussians per wave segment
#define IMG_W 256
#define IMG_H 256
#define JITTER 1e-6f
#define L2E 1.4426950408889634f

// 32 B so the composite loop's wave-uniform read is one s_load_dwordx8.
struct GParam { float mx, my, A, B, D, op, pad0, pad1; };

__device__ __forceinline__ float fexp2(float x)  { return __builtin_amdgcn_exp2f(x); }
__device__ __forceinline__ float frcp(float x)   { return __builtin_amdgcn_rcpf(x); }
__device__ __forceinline__ float fexp(float x)   { return fexp2(x * L2E); }
__device__ __forceinline__ float fsigmoid(float x) { return frcp(1.0f + fexp(-x)); }
__device__ __forceinline__ float ftanh(float x) {
    float t = fexp2(2.0f * L2E * x);      // exp(2x)
    return 1.0f - 2.0f * frcp(t + 1.0f);
}

__device__ __forceinline__ GParam compute_params(int g,
                                                 const float* __restrict__ means,
                                                 const float* __restrict__ scales,
                                                 const float* __restrict__ thetas,
                                                 const float* __restrict__ opacities) {
    GParam p;
    p.mx = ftanh(means[2 * g]);
    p.my = ftanh(means[2 * g + 1]);
    float s2x = fexp(2.0f * scales[2 * g]);       // exp(scales)^2
    float s2y = fexp(2.0f * scales[2 * g + 1]);
    // theta = sigmoid(t)*2pi; v_sin/cos take revolutions -> feed sigmoid raw.
    float rev = fsigmoid(thetas[g]);
    float si = __builtin_amdgcn_sinf(rev);
    float c  = __builtin_amdgcn_cosf(rev);
    float a = c * c * s2x + si * si * s2y + JITTER;
    float b = c * si * (s2x - s2y);
    float d = si * si * s2x + c * c * s2y + JITTER;
    float inv_det = frcp(a * d - b * b);
    // alpha = op * exp2(A*dx^2 + B*dx*dy + D*dy^2)   (log2e, -0.5 folded in)
    p.A = -0.5f * L2E * d * inv_det;
    p.B =  L2E * b * inv_det;        // = -L2E * (-b/det)
    p.D = -0.5f * L2E * a * inv_det;
    p.op = fsigmoid(opacities[g]);
    p.pad0 = 0.0f;
    p.pad1 = 0.0f;
    return p;
}

// Single fused kernel. Block = 512 threads = 8 waves, owns 64 pixels.
// Phase 1: the block redundantly computes ALL 1024 gaussian params (2 per
//          thread) and stores them to a block-private 32 KB region of d_ws.
//          __syncthreads() drains vmcnt(0) -> stores visible in L2; only this
//          block ever scalar-reads this region, and K$/L1 are invalidated at
//          dispatch, so the s_loads below cannot see stale data.
// Phase 2: wave w composites gaussian segment [w*128,(w+1)*128) over the 64
//          pixels (lane = pixel) with wave-uniform s_load_dwordx8 params —
//          zero vector-memory ops in the inner loop (round-3 structure).
// Phase 3: segments combine in order via LDS: (A,T)o(a,t) = (A+T*a, T*t).
__global__ __launch_bounds__(512, 8)
void gs_fused(const float* __restrict__ means,
              const float* __restrict__ scales,
              const float* __restrict__ thetas,
              const float* __restrict__ opacities,
              float* __restrict__ out,
              GParam* __restrict__ ws) {
    __shared__ float2 seg_res[NSEG * 64];

    int tid  = threadIdx.x;
    int lane = tid & 63;

    GParam* __restrict__ myp = ws + (size_t)blockIdx.x * NG;

    // ---- Phase 1: redundant per-block param precompute ----
    myp[tid]       = compute_params(tid,       means, scales, thetas, opacities);
    myp[tid + 512] = compute_params(tid + 512, means, scales, thetas, opacities);
    __syncthreads();

    // ---- Phase 2: per-wave segment composite, 1 pixel per lane ----
    int seg = __builtin_amdgcn_readfirstlane(tid >> 6);
    int p = blockIdx.x * 64 + lane;            // pixel index
    const float step = 2.0f / 255.0f;          // linspace(-1,1,256)
    float x = fmaf((float)(p & 255), step, -1.0f);
    float y = fmaf((float)(p >> 8),  step, -1.0f);

    float acc = 0.0f;
    float T = 1.0f;

    const GParam* __restrict__ gp = myp + seg * SEG_LEN;
    #pragma unroll 4
    for (int g = 0; g < SEG_LEN; ++g) {
        GParam q = gp[g];
        float dx = x - q.mx;
        float dy = y - q.my;
        float e2 = fmaf(dx, fmaf(q.A, dx, q.B * dy), q.D * (dy * dy));
        float alpha = q.op * fexp2(e2);
        acc = fmaf(alpha, T, acc);
        T = fmaf(-alpha, T, T);
    }

    seg_res[seg * 64 + lane] = make_float2(acc, T);
    __syncthreads();

    // ---- Phase 3: in-order combine across segments, write out ----
    if (tid < 64) {
        float A = 0.0f, Tt = 1.0f;
        #pragma unroll
        for (int s = 0; s < NSEG; ++s) {
            float2 v = seg_res[s * 64 + lane];
            A = fmaf(Tt, v.x, A);
            Tt *= v.y;
        }
        // bg = (0,0,0): all 3 channels = A
        float* o = out + 3 * p;
        o[0] = A;
        o[1] = A;
        o[2] = A;
    }
}

extern "C" void kernel_launch(void* const* d_in, const int* in_sizes, int n_in,
                              void* d_out, int out_size, void* d_ws, size_t ws_size,
                              hipStream_t stream) {
    const float* means     = (const float*)d_in[0];
    const float* scales    = (const float*)d_in[1];
    const float* thetas    = (const float*)d_in[2];
    const float* opacities = (const float*)d_in[3];
    float* out = (float*)d_out;
    GParam* ws = (GParam*)d_ws;   // 1024 blocks * 32 KB = 32 MB << ws_size

    gs_fused<<<dim3((IMG_W * IMG_H) / 64), dim3(512), 0, stream>>>(
        means, scales, thetas, opacities, out, ws);
}

// Round 6
// 80.127 us; speedup vs baseline: 1.6376x; 1.6376x over previous
//
#include <hip/hip_runtime.h>
#include <math.h>

#define NG 1024
#define NSEG 8
#define SEG_LEN 128            // gaussians per wave segment
#define IMG_W 256
#define IMG_H 256
#define JITTER 1e-6f
#define L2E 1.4426950408889634f

// 32 B so the composite loop's wave-uniform read is one s_load_dwordx8.
// e2 = c3*x^2 + c4*x*y + c5*y^2 + c1*x + c2*y + c0, alpha = exp2(e2)
// (opacity folded into c0 as +log2(op)).
struct GParam { float c0, c1, c2, c3, c4, c5, pad0, pad1; };
__device__ GParam g_params[NG];

__device__ __forceinline__ float fexp2(float x)  { return __builtin_amdgcn_exp2f(x); }
__device__ __forceinline__ float flog2(float x)  { return __builtin_amdgcn_logf(x); }
__device__ __forceinline__ float frcp(float x)   { return __builtin_amdgcn_rcpf(x); }
__device__ __forceinline__ float fexp(float x)   { return fexp2(x * L2E); }
__device__ __forceinline__ float fsigmoid(float x) { return frcp(1.0f + fexp(-x)); }
__device__ __forceinline__ float ftanh(float x) {
    float t = fexp2(2.0f * L2E * x);      // exp(2x)
    return 1.0f - 2.0f * frcp(t + 1.0f);
}

__global__ __launch_bounds__(256)
void gs_precompute(const float* __restrict__ means,
                   const float* __restrict__ scales,
                   const float* __restrict__ thetas,
                   const float* __restrict__ opacities) {
    int g = blockIdx.x * blockDim.x + threadIdx.x;
    if (g >= NG) return;

    float mx = ftanh(means[2 * g]);
    float my = ftanh(means[2 * g + 1]);
    float s2x = fexp(2.0f * scales[2 * g]);       // exp(scales)^2
    float s2y = fexp(2.0f * scales[2 * g + 1]);
    // theta = sigmoid(t)*2pi; v_sin/cos take revolutions -> feed sigmoid raw.
    float rev = fsigmoid(thetas[g]);
    float si = __builtin_amdgcn_sinf(rev);
    float c  = __builtin_amdgcn_cosf(rev);
    float a = c * c * s2x + si * si * s2y + JITTER;
    float b = c * si * (s2x - s2y);
    float d = si * si * s2x + c * c * s2y + JITTER;
    float inv_det = frcp(a * d - b * b);
    float ia  = d * inv_det;     // Sigma^-1[0][0]
    float ib  = -b * inv_det;    // Sigma^-1[0][1]
    float idd = a * inv_det;     // Sigma^-1[1][1]

    // e2 = P*dx^2 + Q*dx*dy + R*dy^2 + log2(op), P/Q/R fold -0.5*log2(e)
    float P = -0.5f * L2E * ia;
    float Q = -L2E * ib;
    float R = -0.5f * L2E * idd;
    float op = fsigmoid(opacities[g]);

    GParam p;
    p.c3 = P;
    p.c4 = Q;
    p.c5 = R;
    p.c1 = -(2.0f * P * mx + Q * my);
    p.c2 = -(Q * mx + 2.0f * R * my);
    p.c0 = P * mx * mx + Q * mx * my + R * my * my + flog2(op);
    p.pad0 = 0.0f;
    p.pad1 = 0.0f;
    g_params[g] = p;
}

// Block = 512 threads = 8 waves, owns 64 pixels (lane = pixel). Wave w
// composites gaussian segment [w*128,(w+1)*128) with wave-uniform
// s_load_dwordx8 params (scalar pipe — zero vector-mem ops in the loop).
// Inner loop: 5-FMA polynomial chain + exp2 + 2 compositing FMAs.
// Segments combine in order via LDS: (A,T)o(a,t) = (A+T*a, T*t).
__global__ __launch_bounds__(512, 8)
void gs_composite(float* __restrict__ out) {
    __shared__ float2 seg_res[NSEG * 64];

    int tid  = threadIdx.x;
    int lane = tid & 63;
    int seg  = __builtin_amdgcn_readfirstlane(tid >> 6);

    int p = blockIdx.x * 64 + lane;            // pixel index
    const float step = 2.0f / 255.0f;          // linspace(-1,1,256)
    float x = fmaf((float)(p & 255), step, -1.0f);
    float y = fmaf((float)(p >> 8),  step, -1.0f);
    float xx = x * x, xy = x * y, yy = y * y;

    float acc = 0.0f;
    float T = 1.0f;

    const GParam* __restrict__ gp = g_params + seg * SEG_LEN;
    #pragma unroll 8
    for (int g = 0; g < SEG_LEN; ++g) {
        GParam q = gp[g];
        float e2 = fmaf(q.c3, xx,
                   fmaf(q.c4, xy,
                   fmaf(q.c5, yy,
                   fmaf(q.c1, x,
                   fmaf(q.c2, y, q.c0)))));
        float alpha = fexp2(e2);               // opacity folded into c0
        acc = fmaf(alpha, T, acc);
        T = fmaf(-alpha, T, T);
    }

    seg_res[seg * 64 + lane] = make_float2(acc, T);
    __syncthreads();

    // ---- in-order combine across segments, write out ----
    if (tid < 64) {
        float A = 0.0f, Tt = 1.0f;
        #pragma unroll
        for (int s = 0; s < NSEG; ++s) {
            float2 v = seg_res[s * 64 + lane];
            A = fmaf(Tt, v.x, A);
            Tt *= v.y;
        }
        // bg = (0,0,0): all 3 channels = A
        float* o = out + 3 * p;
        o[0] = A;
        o[1] = A;
        o[2] = A;
    }
}

extern "C" void kernel_launch(void* const* d_in, const int* in_sizes, int n_in,
                              void* d_out, int out_size, void* d_ws, size_t ws_size,
                              hipStream_t stream) {
    const float* means     = (const float*)d_in[0];
    const float* scales    = (const float*)d_in[1];
    const float* thetas    = (const float*)d_in[2];
    const float* opacities = (const float*)d_in[3];
    float* out = (float*)d_out;

    gs_precompute<<<dim3(NG / 256), dim3(256), 0, stream>>>(means, scales, thetas, opacities);
    gs_composite<<<dim3((IMG_W * IMG_H) / 64), dim3(512), 0, stream>>>(out);
}

// Round 7
// 68.042 us; speedup vs baseline: 1.9285x; 1.1776x over previous
//
#include <hip/hip_runtime.h>
#include <math.h>

#define NG 1024
#define NWAVES 4               // 256 threads
#define IMG_W 256
#define IMG_H 256
#define TILE 8                 // 8x8 pixel tile per block -> 1024 blocks
#define JITTER 1e-6f
#define L2E 1.4426950408889634f
#define CULL_LOG2_EPS -20.0f   // cull if max alpha over tile < 2^-20 (~1e-6)

__device__ __forceinline__ float fexp2(float x)  { return __builtin_amdgcn_exp2f(x); }
__device__ __forceinline__ float flog2(float x)  { return __builtin_amdgcn_logf(x); }
__device__ __forceinline__ float frcp(float x)   { return __builtin_amdgcn_rcpf(x); }
__device__ __forceinline__ float fsqrt(float x)  { return __builtin_amdgcn_sqrtf(x); }
__device__ __forceinline__ float fexp(float x)   { return fexp2(x * L2E); }
__device__ __forceinline__ float fsigmoid(float x) { return frcp(1.0f + fexp(-x)); }
__device__ __forceinline__ float ftanh(float x) {
    float t = fexp2(2.0f * L2E * x);      // exp(2x)
    return 1.0f - 2.0f * frcp(t + 1.0f);
}

// Single fused kernel. Block = 256 threads = 4 waves, owns one 8x8 pixel tile.
// Phase 1 (4 rounds of 256 gaussians): thread t computes gaussian (256k+t)'s
//   polynomial params e2 = c3 x^2 + c4 xy + c5 y^2 + c1 x + c2 y + c0
//   (opacity folded in as +log2(op)) plus a conservative tile cull bound
//   alpha_max <= op * exp(-0.5 * dmin^2 / lambda_max(Sigma)). Survivors are
//   compacted IN GAUSSIAN-INDEX ORDER into LDS via per-wave ballot + popcount
//   prefix sums (strict order is required by front-to-back compositing).
// Phase 2: wave w composites ordered survivor segment [w*Ns/4,(w+1)*Ns/4)
//   over the 64 tile pixels (lane = pixel), params via LDS broadcast reads.
// Phase 3: segments combine in order: (A,T) o (a,t) = (A + T*a, T*t).
__global__ __launch_bounds__(256, 4)
void gs_tiled(const float* __restrict__ means,
              const float* __restrict__ scales,
              const float* __restrict__ thetas,
              const float* __restrict__ opacities,
              float* __restrict__ out) {
    __shared__ float4 s_c0123[NG];                 // (c0,c1,c2,c3)
    __shared__ float2 s_c45[NG];                   // (c4,c5)
    __shared__ unsigned long long s_mask[4][NWAVES];
    __shared__ float2 s_seg[NWAVES][64];

    int tid  = threadIdx.x;
    int lane = tid & 63;
    int wave = tid >> 6;

    // tile rect in NDC; linspace(-1,1,256) step
    const float step = 2.0f / 255.0f;
    int tx = blockIdx.x & (IMG_W / TILE - 1);
    int ty = blockIdx.x >> 5;
    float rx0 = fmaf((float)(tx * TILE), step, -1.0f);
    float ry0 = fmaf((float)(ty * TILE), step, -1.0f);
    float rx1 = rx0 + (TILE - 1) * step;
    float ry1 = ry0 + (TILE - 1) * step;

    // ---- Phase 1: params + cull + order-preserving compaction ----
    int nsurv = 0;
    for (int k = 0; k < 4; ++k) {
        int g = k * 256 + tid;
        float mx = ftanh(means[2 * g]);
        float my = ftanh(means[2 * g + 1]);
        float s2x = fexp(2.0f * scales[2 * g]);        // exp(scales)^2
        float s2y = fexp(2.0f * scales[2 * g + 1]);
        // theta = sigmoid(t)*2pi; v_sin/cos take revolutions -> feed sigmoid.
        float rev = fsigmoid(thetas[g]);
        float si = __builtin_amdgcn_sinf(rev);
        float c  = __builtin_amdgcn_cosf(rev);
        float a = c * c * s2x + si * si * s2y + JITTER;
        float b = c * si * (s2x - s2y);
        float d = si * si * s2x + c * c * s2y + JITTER;
        float inv_det = frcp(a * d - b * b);
        float P = -0.5f * L2E * d * inv_det;
        float Q =  L2E * b * inv_det;                  // = -L2E * (-b/det)
        float R = -0.5f * L2E * a * inv_det;
        float l2op = flog2(fsigmoid(opacities[g]));
        float c3 = P, c4 = Q, c5 = R;
        float c1 = -(2.0f * P * mx + Q * my);
        float c2 = -(Q * mx + 2.0f * R * my);
        float c0 = P * mx * mx + Q * mx * my + R * my * my + l2op;

        // conservative cull: q >= dmin^2 / lambda_max(Sigma)
        float lam = 0.5f * ((a + d) + fsqrt((a - d) * (a - d) + 4.0f * b * b));
        float Kc = 0.5f * L2E * frcp(lam);
        float ddx = fmaxf(fmaxf(rx0 - mx, mx - rx1), 0.0f);
        float ddy = fmaxf(fmaxf(ry0 - my, my - ry1), 0.0f);
        float d2 = ddx * ddx + ddy * ddy;
        bool keep = (l2op - Kc * d2) >= CULL_LOG2_EPS;

        unsigned long long bal = __ballot(keep);
        if (lane == 0) s_mask[k][wave] = bal;
        __syncthreads();

        // order-preserving position = survivors before me
        int pos = nsurv;
        #pragma unroll
        for (int w = 0; w < NWAVES; ++w) {
            unsigned long long m = s_mask[k][w];
            if (w < wave) pos += __popcll(m);
            nsurv += __popcll(m);
        }
        pos += __popcll(bal & ((1ull << lane) - 1ull));

        if (keep) {
            s_c0123[pos] = make_float4(c0, c1, c2, c3);
            s_c45[pos]   = make_float2(c4, c5);
        }
        __syncthreads();   // masks consumed; param writes land before phase 2
    }

    // ---- Phase 2: per-wave ordered segment composite over 64 pixels ----
    int Ns = nsurv;   // block-uniform (derived from LDS masks identically)
    int sbeg = __builtin_amdgcn_readfirstlane((Ns * wave) >> 2);
    int send = __builtin_amdgcn_readfirstlane((Ns * (wave + 1)) >> 2);

    float x = fmaf((float)(lane & 7), step, rx0);
    float y = fmaf((float)(lane >> 3), step, ry0);
    float xx = x * x, xy = x * y, yy = y * y;

    float acc = 0.0f, T = 1.0f;
    #pragma unroll 4
    for (int i = sbeg; i < send; ++i) {
        float4 q = s_c0123[i];    // broadcast (uniform address)
        float2 r = s_c45[i];
        float e2 = fmaf(q.w, xx,
                   fmaf(r.x, xy,
                   fmaf(r.y, yy,
                   fmaf(q.y, x,
                   fmaf(q.z, y, q.x)))));
        float alpha = fexp2(e2);               // opacity folded into c0
        acc = fmaf(alpha, T, acc);
        T = fmaf(-alpha, T, T);
    }

    s_seg[wave][lane] = make_float2(acc, T);
    __syncthreads();

    // ---- Phase 3: in-order combine, write out ----
    if (tid < 64) {
        float A = 0.0f, Tt = 1.0f;
        #pragma unroll
        for (int s = 0; s < NWAVES; ++s) {
            float2 v = s_seg[s][tid];
            A = fmaf(Tt, v.x, A);
            Tt *= v.y;
        }
        int px = tx * TILE + (tid & 7);
        int py = ty * TILE + (tid >> 3);
        float* o = out + 3 * (py * IMG_W + px);
        o[0] = A;
        o[1] = A;
        o[2] = A;   // bg = (0,0,0)
    }
}

extern "C" void kernel_launch(void* const* d_in, const int* in_sizes, int n_in,
                              void* d_out, int out_size, void* d_ws, size_t ws_size,
                              hipStream_t stream) {
    const float* means     = (const float*)d_in[0];
    const float* scales    = (const float*)d_in[1];
    const float* thetas    = (const float*)d_in[2];
    const float* opacities = (const float*)d_in[3];
    float* out = (float*)d_out;

    gs_tiled<<<dim3((IMG_W / TILE) * (IMG_H / TILE)), dim3(256), 0, stream>>>(
        means, scales, thetas, opacities, out);
}

// Round 8
// 65.084 us; speedup vs baseline: 2.0162x; 1.0455x over previous
//
#include <hip/hip_runtime.h>
#include <math.h>

#define NG 1024
#define NWAVES 8               // 512 threads
#define IMG_W 256
#define IMG_H 256
#define TILE 16                // 16x16 pixel tile per block -> 256 blocks
#define JITTER 1e-6f
#define L2E 1.4426950408889634f
#define CULL_LOG2_EPS -20.0f   // cull if max alpha over tile < 2^-20 (~1e-6)

__device__ __forceinline__ float fexp2(float x)  { return __builtin_amdgcn_exp2f(x); }
__device__ __forceinline__ float flog2(float x)  { return __builtin_amdgcn_logf(x); }
__device__ __forceinline__ float frcp(float x)   { return __builtin_amdgcn_rcpf(x); }
__device__ __forceinline__ float fsqrt(float x)  { return __builtin_amdgcn_sqrtf(x); }
__device__ __forceinline__ float fexp(float x)   { return fexp2(x * L2E); }
__device__ __forceinline__ float fsigmoid(float x) { return frcp(1.0f + fexp(-x)); }
__device__ __forceinline__ float ftanh(float x) {
    float t = fexp2(2.0f * L2E * x);      // exp(2x)
    return 1.0f - 2.0f * frcp(t + 1.0f);
}

// Fused single kernel. Block = 512 threads = 8 waves, owns one 16x16 tile.
// Phase 1 (2 rounds of 512): per-thread param compute + conservative tile
//   cull (alpha_max <= op*exp(-0.5*dmin^2/lambda_max)); survivors compacted
//   IN GAUSSIAN-INDEX ORDER into LDS (ballot + popcount prefix across waves).
// Phase 2: wave w composites ordered survivor segment over all 256 pixels,
//   4 px per lane as a COLUMN (shared x -> 3 FMAs of the quadratic shared).
//   Per-CU LDS cost = blocks/CU * Ns * ~20cyc; at 1 block/CU this balances
//   against VALU (~the point of the 16x16 tile).
// Phase 3: in-order (A,T) monoid combine across the 8 segments, write out.
__global__ __launch_bounds__(512, 2)
void gs_tiled(const float* __restrict__ means,
              const float* __restrict__ scales,
              const float* __restrict__ thetas,
              const float* __restrict__ opacities,
              float* __restrict__ out) {
    __shared__ float4 s_c0123[NG];                 // (c0,c1,c2,c3)
    __shared__ float2 s_c45[NG];                   // (c4,c5)
    __shared__ unsigned long long s_mask[NWAVES];
    __shared__ float2 s_seg[NWAVES][TILE * TILE];  // per-wave (acc,T) per px

    int tid  = threadIdx.x;
    int lane = tid & 63;
    int wave = tid >> 6;

    // tile rect in NDC; linspace(-1,1,256) step
    const float step = 2.0f / 255.0f;
    int tx = blockIdx.x & (IMG_W / TILE - 1);
    int ty = blockIdx.x >> 4;
    float rx0 = fmaf((float)(tx * TILE), step, -1.0f);
    float ry0 = fmaf((float)(ty * TILE), step, -1.0f);
    float rx1 = rx0 + (TILE - 1) * step;
    float ry1 = ry0 + (TILE - 1) * step;

    // ---- Phase 1: params + cull + order-preserving compaction ----
    int nsurv = 0;
    #pragma unroll
    for (int k = 0; k < 2; ++k) {
        int g = k * 512 + tid;
        float mx = ftanh(means[2 * g]);
        float my = ftanh(means[2 * g + 1]);
        float s2x = fexp(2.0f * scales[2 * g]);        // exp(scales)^2
        float s2y = fexp(2.0f * scales[2 * g + 1]);
        // theta = sigmoid(t)*2pi; v_sin/cos take revolutions -> feed sigmoid.
        float rev = fsigmoid(thetas[g]);
        float si = __builtin_amdgcn_sinf(rev);
        float c  = __builtin_amdgcn_cosf(rev);
        float a = c * c * s2x + si * si * s2y + JITTER;
        float b = c * si * (s2x - s2y);
        float d = si * si * s2x + c * c * s2y + JITTER;
        float inv_det = frcp(a * d - b * b);
        float P = -0.5f * L2E * d * inv_det;
        float Q =  L2E * b * inv_det;                  // = -L2E * (-b/det)
        float R = -0.5f * L2E * a * inv_det;
        float l2op = flog2(fsigmoid(opacities[g]));
        float c1 = -(2.0f * P * mx + Q * my);
        float c2 = -(Q * mx + 2.0f * R * my);
        float c0 = P * mx * mx + Q * mx * my + R * my * my + l2op;

        // conservative cull: q >= dmin^2 / lambda_max(Sigma)
        float lam = 0.5f * ((a + d) + fsqrt((a - d) * (a - d) + 4.0f * b * b));
        float Kc = 0.5f * L2E * frcp(lam);
        float ddx = fmaxf(fmaxf(rx0 - mx, mx - rx1), 0.0f);
        float ddy = fmaxf(fmaxf(ry0 - my, my - ry1), 0.0f);
        float d2 = ddx * ddx + ddy * ddy;
        bool keep = (l2op - Kc * d2) >= CULL_LOG2_EPS;

        unsigned long long bal = __ballot(keep);
        if (lane == 0) s_mask[wave] = bal;
        __syncthreads();

        // order-preserving position = survivors before me (across 8 waves)
        int pos = nsurv;
        #pragma unroll
        for (int w = 0; w < NWAVES; ++w) {
            unsigned long long m = s_mask[w];
            if (w < wave) pos += __popcll(m);
            nsurv += __popcll(m);
        }
        pos += __popcll(bal & ((1ull << lane) - 1ull));

        if (keep) {
            s_c0123[pos] = make_float4(c0, c1, c2, P);
            s_c45[pos]   = make_float2(Q, R);
        }
        __syncthreads();   // masks consumed & params landed before next round
    }

    // ---- Phase 2: per-wave ordered segment over 256 px (4 px/lane col) ----
    int Ns = nsurv;   // block-uniform
    int sbeg = __builtin_amdgcn_readfirstlane((Ns * wave) >> 3);
    int send = __builtin_amdgcn_readfirstlane((Ns * (wave + 1)) >> 3);

    int col  = lane & 15;          // shared x per lane
    int rowg = lane >> 4;          // 4 row-groups; lane covers rows rowg*4+k
    float x  = fmaf((float)col, step, rx0);
    float y0 = fmaf((float)(rowg * 4 + 0), step, ry0);
    float y1 = y0 + step;
    float y2 = y1 + step;
    float y3 = y2 + step;

    float acc0 = 0.f, T0 = 1.f, acc1 = 0.f, T1 = 1.f;
    float acc2 = 0.f, T2 = 1.f, acc3 = 0.f, T3 = 1.f;

    #pragma unroll 4
    for (int i = sbeg; i < send; ++i) {
        float4 q = s_c0123[i];     // broadcast (uniform address)
        float2 r = s_c45[i];
        // e2(x,y) = (c3x^2 + c1x + c0) + (c4x + c2)y + c5y^2
        float t1 = fmaf(x, fmaf(q.w, x, q.y), q.x);   // shared over column
        float u  = fmaf(r.x, x, q.z);                 // shared over column
        float e, al;
        e = fmaf(y0, fmaf(r.y, y0, u), t1); al = fexp2(e);
        acc0 = fmaf(al, T0, acc0); T0 = fmaf(-al, T0, T0);
        e = fmaf(y1, fmaf(r.y, y1, u), t1); al = fexp2(e);
        acc1 = fmaf(al, T1, acc1); T1 = fmaf(-al, T1, T1);
        e = fmaf(y2, fmaf(r.y, y2, u), t1); al = fexp2(e);
        acc2 = fmaf(al, T2, acc2); T2 = fmaf(-al, T2, T2);
        e = fmaf(y3, fmaf(r.y, y3, u), t1); al = fexp2(e);
        acc3 = fmaf(al, T3, acc3); T3 = fmaf(-al, T3, T3);
    }

    int pxb = (rowg * 4) * TILE + col;
    s_seg[wave][pxb]            = make_float2(acc0, T0);
    s_seg[wave][pxb + TILE]     = make_float2(acc1, T1);
    s_seg[wave][pxb + 2 * TILE] = make_float2(acc2, T2);
    s_seg[wave][pxb + 3 * TILE] = make_float2(acc3, T3);
    __syncthreads();

    // ---- Phase 3: in-order combine across 8 segments, write out ----
    if (tid < TILE * TILE) {
        float A = 0.0f, Tt = 1.0f;
        #pragma unroll
        for (int s = 0; s < NWAVES; ++s) {
            float2 v = s_seg[s][tid];
            A = fmaf(Tt, v.x, A);
            Tt *= v.y;
        }
        int px = tx * TILE + (tid & 15);
        int py = ty * TILE + (tid >> 4);
        float* o = out + 3 * (py * IMG_W + px);
        o[0] = A;
        o[1] = A;
        o[2] = A;   // bg = (0,0,0)
    }
}

extern "C" void kernel_launch(void* const* d_in, const int* in_sizes, int n_in,
                              void* d_out, int out_size, void* d_ws, size_t ws_size,
                              hipStream_t stream) {
    const float* means     = (const float*)d_in[0];
    const float* scales    = (const float*)d_in[1];
    const float* thetas    = (const float*)d_in[2];
    const float* opacities = (const float*)d_in[3];
    float* out = (float*)d_out;

    gs_tiled<<<dim3((IMG_W / TILE) * (IMG_H / TILE)), dim3(512), 0, stream>>>(
        means, scales, thetas, opacities, out);
}

// Round 9
// 63.316 us; speedup vs baseline: 2.0725x; 1.0279x over previous
//
#include <hip/hip_runtime.h>
#include <math.h>

#define NG 1024
#define NWAVES 8               // 512 threads
#define IMG_W 256
#define IMG_H 256
#define TILE 16                // 16x16 pixel tile per block -> 256 blocks
#define JITTER 1e-6f
#define L2E 1.4426950408889634f
#define CULL_LOG2_EPS -16.0f   // cull if exact max alpha over tile < 2^-16

__device__ __forceinline__ float fexp2(float x)  { return __builtin_amdgcn_exp2f(x); }
__device__ __forceinline__ float flog2(float x)  { return __builtin_amdgcn_logf(x); }
__device__ __forceinline__ float frcp(float x)   { return __builtin_amdgcn_rcpf(x); }
__device__ __forceinline__ float fexp(float x)   { return fexp2(x * L2E); }
__device__ __forceinline__ float fsigmoid(float x) { return frcp(1.0f + fexp(-x)); }
__device__ __forceinline__ float ftanh(float x) {
    float t = fexp2(2.0f * L2E * x);      // exp(2x)
    return 1.0f - 2.0f * frcp(t + 1.0f);
}

// Fused single kernel. Block = 512 threads = 8 waves, owns one 16x16 tile.
// Phase 1 (2 rounds of 512): per-thread param compute + EXACT tile cull:
//   e2(x,y) is a concave quadratic, so max over the rect is either at the
//   mean (if inside) or on one of the 4 edges, each a 1-D concave quadratic
//   maximized at its clamped vertex. keep iff max e2 >= log2(eps).
//   Survivors compacted IN GAUSSIAN-INDEX ORDER into LDS (ballot + popcount
//   prefix across waves) — strict order required by compositing.
// Phase 2: wave w composites ordered survivor segment over all 256 pixels,
//   4 px per lane as a COLUMN (shared x -> 3 FMAs shared per gaussian).
// Phase 3: in-order (A,T) monoid combine across the 8 segments, write out.
__global__ __launch_bounds__(512, 2)
void gs_tiled(const float* __restrict__ means,
              const float* __restrict__ scales,
              const float* __restrict__ thetas,
              const float* __restrict__ opacities,
              float* __restrict__ out) {
    __shared__ float4 s_c0123[NG];                 // (c0,c1,c2,c3)
    __shared__ float2 s_c45[NG];                   // (c4,c5)
    __shared__ unsigned long long s_mask[NWAVES];
    __shared__ float2 s_seg[NWAVES][TILE * TILE];  // per-wave (acc,T) per px

    int tid  = threadIdx.x;
    int lane = tid & 63;
    int wave = tid >> 6;

    // tile rect in NDC; linspace(-1,1,256) step
    const float step = 2.0f / 255.0f;
    int tx = blockIdx.x & (IMG_W / TILE - 1);
    int ty = blockIdx.x >> 4;
    float rx0 = fmaf((float)(tx * TILE), step, -1.0f);
    float ry0 = fmaf((float)(ty * TILE), step, -1.0f);
    float rx1 = rx0 + (TILE - 1) * step;
    float ry1 = ry0 + (TILE - 1) * step;

    // ---- Phase 1: params + exact cull + order-preserving compaction ----
    int nsurv = 0;
    #pragma unroll
    for (int k = 0; k < 2; ++k) {
        int g = k * 512 + tid;
        float mx = ftanh(means[2 * g]);
        float my = ftanh(means[2 * g + 1]);
        float s2x = fexp(2.0f * scales[2 * g]);        // exp(scales)^2
        float s2y = fexp(2.0f * scales[2 * g + 1]);
        // theta = sigmoid(t)*2pi; v_sin/cos take revolutions -> feed sigmoid.
        float rev = fsigmoid(thetas[g]);
        float si = __builtin_amdgcn_sinf(rev);
        float c  = __builtin_amdgcn_cosf(rev);
        float a = c * c * s2x + si * si * s2y + JITTER;
        float b = c * si * (s2x - s2y);
        float d = si * si * s2x + c * c * s2y + JITTER;
        float inv_det = frcp(a * d - b * b);
        float c3 = -0.5f * L2E * d * inv_det;          // P  (< 0)
        float c4 =  L2E * b * inv_det;                 // Q
        float c5 = -0.5f * L2E * a * inv_det;          // R  (< 0)
        float l2op = flog2(fsigmoid(opacities[g]));
        float c1 = -(2.0f * c3 * mx + c4 * my);
        float c2 = -(c4 * mx + 2.0f * c5 * my);
        float c0 = c3 * mx * mx + c4 * mx * my + c5 * my * my + l2op;

        // Exact max of concave quadratic e2 over the rect:
        float e2max;
        if (mx >= rx0 && mx <= rx1 && my >= ry0 && my <= ry1) {
            e2max = l2op;                              // mean inside rect
        } else {
            float h3 = frcp(c3) * 0.5f;                // 1/(2c3)
            float h5 = frcp(c5) * 0.5f;                // 1/(2c5)
            // edge x = rx0 / rx1: f(y) = c5 y^2 + (c4 e + c2) y + (c3e^2+c1e+c0)
            float B0 = fmaf(c4, rx0, c2);
            float C0 = fmaf(rx0, fmaf(c3, rx0, c1), c0);
            float yv0 = fminf(fmaxf(-B0 * h5, ry0), ry1);
            float v0 = fmaf(yv0, fmaf(c5, yv0, B0), C0);
            float B1 = fmaf(c4, rx1, c2);
            float C1 = fmaf(rx1, fmaf(c3, rx1, c1), c0);
            float yv1 = fminf(fmaxf(-B1 * h5, ry0), ry1);
            float v1 = fmaf(yv1, fmaf(c5, yv1, B1), C1);
            // edge y = ry0 / ry1: f(x) = c3 x^2 + (c4 e + c1) x + (c5e^2+c2e+c0)
            float B2 = fmaf(c4, ry0, c1);
            float C2 = fmaf(ry0, fmaf(c5, ry0, c2), c0);
            float xv2 = fminf(fmaxf(-B2 * h3, rx0), rx1);
            float v2 = fmaf(xv2, fmaf(c3, xv2, B2), C2);
            float B3 = fmaf(c4, ry1, c1);
            float C3 = fmaf(ry1, fmaf(c5, ry1, c2), c0);
            float xv3 = fminf(fmaxf(-B3 * h3, rx0), rx1);
            float v3 = fmaf(xv3, fmaf(c3, xv3, B3), C3);
            e2max = fmaxf(fmaxf(v0, v1), fmaxf(v2, v3));
        }
        bool keep = e2max >= CULL_LOG2_EPS;

        unsigned long long bal = __ballot(keep);
        if (lane == 0) s_mask[wave] = bal;
        __syncthreads();

        // order-preserving position = survivors before me (across 8 waves)
        int pos = nsurv;
        #pragma unroll
        for (int w = 0; w < NWAVES; ++w) {
            unsigned long long m = s_mask[w];
            if (w < wave) pos += __popcll(m);
            nsurv += __popcll(m);
        }
        pos += __popcll(bal & ((1ull << lane) - 1ull));

        if (keep) {
            s_c0123[pos] = make_float4(c0, c1, c2, c3);
            s_c45[pos]   = make_float2(c4, c5);
        }
        __syncthreads();   // masks consumed & params landed before next round
    }

    // ---- Phase 2: per-wave ordered segment over 256 px (4 px/lane col) ----
    int Ns = nsurv;   // block-uniform
    int sbeg = __builtin_amdgcn_readfirstlane((Ns * wave) >> 3);
    int send = __builtin_amdgcn_readfirstlane((Ns * (wave + 1)) >> 3);

    int col  = lane & 15;          // shared x per lane
    int rowg = lane >> 4;          // lane covers rows rowg*4 .. rowg*4+3
    float x  = fmaf((float)col, step, rx0);
    float y0 = fmaf((float)(rowg * 4 + 0), step, ry0);
    float y1 = y0 + step;
    float y2 = y1 + step;
    float y3 = y2 + step;

    float acc0 = 0.f, T0 = 1.f, acc1 = 0.f, T1 = 1.f;
    float acc2 = 0.f, T2 = 1.f, acc3 = 0.f, T3 = 1.f;

    #pragma unroll 4
    for (int i = sbeg; i < send; ++i) {
        float4 q = s_c0123[i];     // broadcast (uniform address)
        float2 r = s_c45[i];
        // e2(x,y) = (c3x^2 + c1x + c0) + (c4x + c2)y + c5y^2
        float t1 = fmaf(x, fmaf(q.w, x, q.y), q.x);   // shared over column
        float u  = fmaf(r.x, x, q.z);                 // shared over column
        float e, al;
        e = fmaf(y0, fmaf(r.y, y0, u), t1); al = fexp2(e);
        acc0 = fmaf(al, T0, acc0); T0 = fmaf(-al, T0, T0);
        e = fmaf(y1, fmaf(r.y, y1, u), t1); al = fexp2(e);
        acc1 = fmaf(al, T1, acc1); T1 = fmaf(-al, T1, T1);
        e = fmaf(y2, fmaf(r.y, y2, u), t1); al = fexp2(e);
        acc2 = fmaf(al, T2, acc2); T2 = fmaf(-al, T2, T2);
        e = fmaf(y3, fmaf(r.y, y3, u), t1); al = fexp2(e);
        acc3 = fmaf(al, T3, acc3); T3 = fmaf(-al, T3, T3);
    }

    int pxb = (rowg * 4) * TILE + col;
    s_seg[wave][pxb]            = make_float2(acc0, T0);
    s_seg[wave][pxb + TILE]     = make_float2(acc1, T1);
    s_seg[wave][pxb + 2 * TILE] = make_float2(acc2, T2);
    s_seg[wave][pxb + 3 * TILE] = make_float2(acc3, T3);
    __syncthreads();

    // ---- Phase 3: in-order combine across 8 segments, write out ----
    if (tid < TILE * TILE) {
        float A = 0.0f, Tt = 1.0f;
        #pragma unroll
        for (int s = 0; s < NWAVES; ++s) {
            float2 v = s_seg[s][tid];
            A = fmaf(Tt, v.x, A);
            Tt *= v.y;
        }
        int px = tx * TILE + (tid & 15);
        int py = ty * TILE + (tid >> 4);
        float* o = out + 3 * (py * IMG_W + px);
        o[0] = A;
        o[1] = A;
        o[2] = A;   // bg = (0,0,0)
    }
}

extern "C" void kernel_launch(void* const* d_in, const int* in_sizes, int n_in,
                              void* d_out, int out_size, void* d_ws, size_t ws_size,
                              hipStream_t stream) {
    const float* means     = (const float*)d_in[0];
    const float* scales    = (const float*)d_in[1];
    const float* thetas    = (const float*)d_in[2];
    const float* opacities = (const float*)d_in[3];
    float* out = (float*)d_out;

    gs_tiled<<<dim3((IMG_W / TILE) * (IMG_H / TILE)), dim3(512), 0, stream>>>(
        means, scales, thetas, opacities, out);
}

// Round 10
// 63.155 us; speedup vs baseline: 2.0777x; 1.0026x over previous
//
#include <hip/hip_runtime.h>
#include <math.h>

#define NG 1024
#define NWAVES 8               // 512 threads
#define IMG_W 256
#define IMG_H 256
#define TILE 16                // 16x16 pixel tile per block -> 256 blocks
#define JITTER 1e-6f
#define L2E 1.4426950408889634f
#define CULL_LOG2_EPS -15.0f   // cull if exact max alpha over tile < 2^-15

__device__ __forceinline__ float fexp2(float x)  { return __builtin_amdgcn_exp2f(x); }
__device__ __forceinline__ float flog2(float x)  { return __builtin_amdgcn_logf(x); }
__device__ __forceinline__ float frcp(float x)   { return __builtin_amdgcn_rcpf(x); }
__device__ __forceinline__ float fexp(float x)   { return fexp2(x * L2E); }
__device__ __forceinline__ float fsigmoid(float x) { return frcp(1.0f + fexp(-x)); }
__device__ __forceinline__ float ftanh(float x) {
    float t = fexp2(2.0f * L2E * x);      // exp(2x)
    return 1.0f - 2.0f * frcp(t + 1.0f);
}

// Fused single kernel. Block = 512 threads = 8 waves, owns one 16x16 tile.
// Phase 1 (2 rounds of 512): per-thread param compute + EXACT tile cull
//   (concave quadratic max over rect: mean if inside, else 4 clamped edge
//   vertices). Survivors compacted IN GAUSSIAN-INDEX ORDER into LDS
//   (ballot + popcount prefix across waves; double-buffered masks -> one
//   barrier per round + one final).
// Phase 2: wave w composites ordered survivor segment over all 256 pixels,
//   4 px per lane as a COLUMN (shared x -> 3 FMAs shared per gaussian);
//   records software-pipelined (next prefetched while current computes).
// Phase 3: in-order (A,T) monoid combine across the 8 segments, write out.
__global__ __launch_bounds__(512, 2)
void gs_tiled(const float* __restrict__ means,
              const float* __restrict__ scales,
              const float* __restrict__ thetas,
              const float* __restrict__ opacities,
              float* __restrict__ out) {
    __shared__ float4 s_c0123[NG];                 // (c0,c1,c2,c3)
    __shared__ float2 s_c45[NG];                   // (c4,c5)
    __shared__ unsigned long long s_mask[2][NWAVES];
    __shared__ float2 s_seg[NWAVES][TILE * TILE];  // per-wave (acc,T) per px

    int tid  = threadIdx.x;
    int lane = tid & 63;
    int wave = tid >> 6;

    // tile rect in NDC; linspace(-1,1,256) step
    const float step = 2.0f / 255.0f;
    int tx = blockIdx.x & (IMG_W / TILE - 1);
    int ty = blockIdx.x >> 4;
    float rx0 = fmaf((float)(tx * TILE), step, -1.0f);
    float ry0 = fmaf((float)(ty * TILE), step, -1.0f);
    float rx1 = rx0 + (TILE - 1) * step;
    float ry1 = ry0 + (TILE - 1) * step;

    // ---- Phase 1: params + exact cull + order-preserving compaction ----
    int nsurv = 0;
    #pragma unroll
    for (int k = 0; k < 2; ++k) {
        int g = k * 512 + tid;
        float mx = ftanh(means[2 * g]);
        float my = ftanh(means[2 * g + 1]);
        float s2x = fexp(2.0f * scales[2 * g]);        // exp(scales)^2
        float s2y = fexp(2.0f * scales[2 * g + 1]);
        // theta = sigmoid(t)*2pi; v_sin/cos take revolutions -> feed sigmoid.
        float rev = fsigmoid(thetas[g]);
        float si = __builtin_amdgcn_sinf(rev);
        float c  = __builtin_amdgcn_cosf(rev);
        float a = c * c * s2x + si * si * s2y + JITTER;
        float b = c * si * (s2x - s2y);
        float d = si * si * s2x + c * c * s2y + JITTER;
        float inv_det = frcp(a * d - b * b);
        float c3 = -0.5f * L2E * d * inv_det;          // P  (< 0)
        float c4 =  L2E * b * inv_det;                 // Q
        float c5 = -0.5f * L2E * a * inv_det;          // R  (< 0)
        float l2op = flog2(fsigmoid(opacities[g]));
        float c1 = -(2.0f * c3 * mx + c4 * my);
        float c2 = -(c4 * mx + 2.0f * c5 * my);
        float c0 = c3 * mx * mx + c4 * mx * my + c5 * my * my + l2op;

        // Exact max of concave quadratic e2 over the rect (branchless-ish):
        float h3 = frcp(c3) * 0.5f;                // 1/(2c3)
        float h5 = frcp(c5) * 0.5f;                // 1/(2c5)
        // edges x = rx0 / rx1: f(y) = c5 y^2 + (c4 e + c2) y + (...)
        float B0 = fmaf(c4, rx0, c2);
        float C0 = fmaf(rx0, fmaf(c3, rx0, c1), c0);
        float yv0 = fminf(fmaxf(-B0 * h5, ry0), ry1);
        float v0 = fmaf(yv0, fmaf(c5, yv0, B0), C0);
        float B1 = fmaf(c4, rx1, c2);
        float C1 = fmaf(rx1, fmaf(c3, rx1, c1), c0);
        float yv1 = fminf(fmaxf(-B1 * h5, ry0), ry1);
        float v1 = fmaf(yv1, fmaf(c5, yv1, B1), C1);
        // edges y = ry0 / ry1: f(x) = c3 x^2 + (c4 e + c1) x + (...)
        float B2 = fmaf(c4, ry0, c1);
        float C2 = fmaf(ry0, fmaf(c5, ry0, c2), c0);
        float xv2 = fminf(fmaxf(-B2 * h3, rx0), rx1);
        float v2 = fmaf(xv2, fmaf(c3, xv2, B2), C2);
        float B3 = fmaf(c4, ry1, c1);
        float C3 = fmaf(ry1, fmaf(c5, ry1, c2), c0);
        float xv3 = fminf(fmaxf(-B3 * h3, rx0), rx1);
        float v3 = fmaf(xv3, fmaf(c3, xv3, B3), C3);
        float e2max = fmaxf(fmaxf(v0, v1), fmaxf(v2, v3));
        bool inside = (mx >= rx0) & (mx <= rx1) & (my >= ry0) & (my <= ry1);
        e2max = inside ? l2op : e2max;
        bool keep = e2max >= CULL_LOG2_EPS;

        unsigned long long bal = __ballot(keep);
        if (lane == 0) s_mask[k][wave] = bal;
        __syncthreads();   // masks of round k visible to all waves

        // order-preserving position = survivors before me (across 8 waves)
        int pos = nsurv;
        #pragma unroll
        for (int w = 0; w < NWAVES; ++w) {
            unsigned long long m = s_mask[k][w];
            if (w < wave) pos += __popcll(m);
            nsurv += __popcll(m);
        }
        pos += __popcll(bal & ((1ull << lane) - 1ull));

        if (keep) {
            s_c0123[pos] = make_float4(c0, c1, c2, c3);
            s_c45[pos]   = make_float2(c4, c5);
        }
        // rounds write disjoint mask buffers and disjoint param slots:
        // no barrier needed until params are consumed below.
    }
    __syncthreads();       // all param writes landed before phase 2

    // ---- Phase 2: per-wave ordered segment over 256 px (4 px/lane col) ----
    int Ns = nsurv;   // block-uniform
    int sbeg = __builtin_amdgcn_readfirstlane((Ns * wave) >> 3);
    int send = __builtin_amdgcn_readfirstlane((Ns * (wave + 1)) >> 3);

    int col  = lane & 15;          // shared x per lane
    int rowg = lane >> 4;          // lane covers rows rowg*4 .. rowg*4+3
    float x  = fmaf((float)col, step, rx0);
    float y0 = fmaf((float)(rowg * 4 + 0), step, ry0);
    float y1 = y0 + step;
    float y2 = y1 + step;
    float y3 = y2 + step;

    float acc0 = 0.f, T0 = 1.f, acc1 = 0.f, T1 = 1.f;
    float acc2 = 0.f, T2 = 1.f, acc3 = 0.f, T3 = 1.f;

    if (sbeg < send) {
        // software pipeline: prefetch next record while computing current
        float4 q = s_c0123[sbeg];
        float2 r = s_c45[sbeg];
        #pragma unroll 8
        for (int i = sbeg; i < send; ++i) {
            float4 qn; float2 rn;
            if (i + 1 < send) { qn = s_c0123[i + 1]; rn = s_c45[i + 1]; }
            // e2(x,y) = (c3x^2 + c1x + c0) + (c4x + c2)y + c5y^2
            float t1 = fmaf(x, fmaf(q.w, x, q.y), q.x);   // shared over column
            float u  = fmaf(r.x, x, q.z);                 // shared over column
            float e, al;
            e = fmaf(y0, fmaf(r.y, y0, u), t1); al = fexp2(e);
            acc0 = fmaf(al, T0, acc0); T0 = fmaf(-al, T0, T0);
            e = fmaf(y1, fmaf(r.y, y1, u), t1); al = fexp2(e);
            acc1 = fmaf(al, T1, acc1); T1 = fmaf(-al, T1, T1);
            e = fmaf(y2, fmaf(r.y, y2, u), t1); al = fexp2(e);
            acc2 = fmaf(al, T2, acc2); T2 = fmaf(-al, T2, T2);
            e = fmaf(y3, fmaf(r.y, y3, u), t1); al = fexp2(e);
            acc3 = fmaf(al, T3, acc3); T3 = fmaf(-al, T3, T3);
            q = qn; r = rn;
        }
    }

    int pxb = (rowg * 4) * TILE + col;
    s_seg[wave][pxb]            = make_float2(acc0, T0);
    s_seg[wave][pxb + TILE]     = make_float2(acc1, T1);
    s_seg[wave][pxb + 2 * TILE] = make_float2(acc2, T2);
    s_seg[wave][pxb + 3 * TILE] = make_float2(acc3, T3);
    __syncthreads();

    // ---- Phase 3: in-order combine across 8 segments, write out ----
    if (tid < TILE * TILE) {
        float A = 0.0f, Tt = 1.0f;
        #pragma unroll
        for (int s = 0; s < NWAVES; ++s) {
            float2 v = s_seg[s][tid];
            A = fmaf(Tt, v.x, A);
            Tt *= v.y;
        }
        int px = tx * TILE + (tid & 15);
        int py = ty * TILE + (tid >> 4);
        float* o = out + 3 * (py * IMG_W + px);
        o[0] = A;
        o[1] = A;
        o[2] = A;   // bg = (0,0,0)
    }
}

extern "C" void kernel_launch(void* const* d_in, const int* in_sizes, int n_in,
                              void* d_out, int out_size, void* d_ws, size_t ws_size,
                              hipStream_t stream) {
    const float* means     = (const float*)d_in[0];
    const float* scales    = (const float*)d_in[1];
    const float* thetas    = (const float*)d_in[2];
    const float* opacities = (const float*)d_in[3];
    float* out = (float*)d_out;

    gs_tiled<<<dim3((IMG_W / TILE) * (IMG_H / TILE)), dim3(512), 0, stream>>>(
        means, scales, thetas, opacities, out);
}